// Round 3
// baseline (4952.195 us; speedup 1.0000x reference)
//
#include <hip/hip_runtime.h>
#include <hip/hip_bf16.h>
#include <cstdint>
#include <cstddef>

// Problem constants
#define H_    1024
#define DI_   2048
#define DS_   16
#define DTR_  64
#define NL_   4
#define LLM_  4096
#define B_    4
#define L_    1024
#define MEMID 50279
#define KTOK  16
#define MROWS (B_*L_)   // 4096

using bf16 = __hip_bfloat16;
typedef __attribute__((ext_vector_type(8))) short short8;
typedef __attribute__((ext_vector_type(4))) float floatx4;

__device__ __forceinline__ float b2f(bf16 v){ return __bfloat162float(v); }
__device__ __forceinline__ bf16  f2b(float v){ return __float2bfloat16(v); }

// ---------------- f32 -> bf16 convert (weights)
__global__ void cvt_kernel(const float* __restrict__ src, bf16* __restrict__ dst, int n)
{
    int i = blockIdx.x*256 + threadIdx.x;
    if (i < n) dst[i] = f2b(src[i]);
}

// ---------------- embed gather: h[row,:] = embed[ids[row],:] (f32 -> f32)
__global__ void embed_kernel(const int* __restrict__ ids,
                             const float* __restrict__ emb,
                             float* __restrict__ h)
{
    int row = blockIdx.x;                       // 0..4095
    int id  = ids[row];
    const float* src = emb + (size_t)id * H_;
    float* dst = h + (size_t)row * H_;
    for (int i = threadIdx.x; i < H_; i += 256) dst[i] = src[i];
}

// ---------------- rmsnorm over H=1024, one block per row, output bf16
__global__ void rmsnorm_kernel(const float* __restrict__ h,
                               const float* __restrict__ w,
                               bf16* __restrict__ out)
{
    int row = blockIdx.x;
    const float* x = h + (size_t)row * H_;
    float v[4]; float ss = 0.f;
    #pragma unroll
    for (int i = 0; i < 4; i++){ v[i] = x[threadIdx.x + 256*i]; ss += v[i]*v[i]; }
    #pragma unroll
    for (int off = 32; off; off >>= 1) ss += __shfl_down(ss, off, 64);
    __shared__ float red[4];
    __shared__ float scale_s;
    int lane = threadIdx.x & 63, wv = threadIdx.x >> 6;
    if (lane == 0) red[wv] = ss;
    __syncthreads();
    if (threadIdx.x == 0){
        float t = red[0]+red[1]+red[2]+red[3];
        scale_s = rsqrtf(t * (1.f/H_) + 1e-5f);
    }
    __syncthreads();
    float sc = scale_s;
    #pragma unroll
    for (int i = 0; i < 4; i++){
        int c = threadIdx.x + 256*i;
        out[(size_t)row*H_ + c] = f2b(v[i] * sc * w[c]);
    }
}

// ---------------- generic MFMA GEMM: C[m,n] = sum_k A[m,k]*B[n,k]  (A MxK, B NxK, both bf16 K-contig)
// mode 0: Cf = acc + bias?[n]          (fp32 store)
// mode 1: Cb = bf16(softplus(acc+bias[n]))
// mode 2: Cf += acc                    (fp32 residual in-place)
// mode 3: Cb = bf16(acc)               (bf16 store)
__launch_bounds__(256)
__global__ void gemm_bt(const bf16* __restrict__ A, int lda,
                        const bf16* __restrict__ Bm, int ldb,
                        int M, int N, int K,
                        float* __restrict__ Cf, bf16* __restrict__ Cb, int ldc,
                        const float* __restrict__ bias, int mode)
{
    int lane = threadIdx.x & 63;
    int wv   = threadIdx.x >> 6;          // 4 waves, 2x2 of 64x64
    int quad = lane >> 4, r16 = lane & 15;
    int m_base = blockIdx.y*128 + (wv>>1)*64;
    int n_base = blockIdx.x*128 + (wv&1)*64;

    floatx4 acc[4][4];
    #pragma unroll
    for (int i=0;i<4;i++)
        #pragma unroll
        for (int j=0;j<4;j++) acc[i][j] = (floatx4){0.f,0.f,0.f,0.f};
    short8 zero8 = (short8){0,0,0,0,0,0,0,0};

    for (int k0 = 0; k0 < K; k0 += 32){
        int kf = k0 + quad*8;
        short8 a[4], b[4];
        #pragma unroll
        for (int i=0;i<4;i++){
            int row = m_base + i*16 + r16;
            a[i] = (row < M) ? *(const short8*)(A + (size_t)row*lda + kf) : zero8;
            int col = n_base + i*16 + r16;
            b[i] = (col < N) ? *(const short8*)(Bm + (size_t)col*ldb + kf) : zero8;
        }
        #pragma unroll
        for (int i=0;i<4;i++)
            #pragma unroll
            for (int j=0;j<4;j++)
                acc[i][j] = __builtin_amdgcn_mfma_f32_16x16x32_bf16(a[i], b[j], acc[i][j], 0, 0, 0);
    }

    #pragma unroll
    for (int i=0;i<4;i++)
        #pragma unroll
        for (int j=0;j<4;j++){
            #pragma unroll
            for (int rr=0;rr<4;rr++){
                int m = m_base + i*16 + quad*4 + rr;   // row = (lane>>4)*4+reg
                int n = n_base + j*16 + r16;           // col = lane&15
                if (m < M && n < N){
                    float v = acc[i][j][rr];
                    if (mode == 0){
                        Cf[(size_t)m*ldc + n] = v + (bias ? bias[n] : 0.f);
                    } else if (mode == 1){
                        float xx = v + bias[n];
                        float sp = (xx > 20.f) ? xx : log1pf(__expf(xx));
                        Cb[(size_t)m*ldc + n] = f2b(sp);
                    } else if (mode == 2){
                        Cf[(size_t)m*ldc + n] += v;
                    } else {
                        Cb[(size_t)m*ldc + n] = f2b(v);
                    }
                }
            }
        }
}

// ---------------- causal depthwise conv (k=4, left pad 3) + silu.  x = xz[:, :DI]
__global__ void conv_silu_kernel(const bf16* __restrict__ xz,
                                 const float* __restrict__ cw,
                                 const float* __restrict__ cb,
                                 bf16* __restrict__ u)
{
    int idx = blockIdx.x*256 + threadIdx.x;     // < 4096*2048
    int d    = idx & (DI_-1);
    int mrow = idx >> 11;
    int t = mrow & (L_-1);
    int b = mrow >> 10;
    float acc = cb[d];
    #pragma unroll
    for (int k=0;k<4;k++){
        int tt = t - 3 + k;
        if (tt >= 0)
            acc += b2f(xz[((size_t)((b<<10)+tt))*(2*DI_) + d]) * cw[d*4+k];
    }
    float s = acc / (1.f + __expf(-acc));
    u[idx] = f2b(s);
}

// ---------------- selective scan + gate fused.
// lane = (ch(4) x state(16)) per wave; 2048 waves total.
// Writes gated output IN-PLACE into the (dead) x-half of xz.
__global__ void scan_gate_kernel(const bf16* __restrict__ dt,
                                 const bf16* __restrict__ u,
                                 const bf16* __restrict__ ssm,
                                 const float* __restrict__ A_log,
                                 const float* __restrict__ Dp,
                                 bf16* __restrict__ xz)
{
    int lane  = threadIdx.x & 63;
    int wv    = threadIdx.x >> 6;
    int s_idx = lane & 15;
    int ch    = lane >> 4;
    int c = blockIdx.x*16 + wv*4 + ch;      // 0..8191 channel (b,d)
    int d = c & (DI_-1);
    int b = c >> 11;
    float A_s = -__expf(A_log[d*DS_ + s_idx]);
    float Dv  = Dp[d];
    float state = 0.f;
    for (int t = 0; t < L_; t++){
        int row = (b<<10) + t;
        float dt_v = b2f(dt[(size_t)row*DI_ + d]);
        float u_v  = b2f(u[(size_t)row*DI_ + d]);
        float B_v  = b2f(ssm[(size_t)row*96 + 64 + s_idx]);
        float C_v  = b2f(ssm[(size_t)row*96 + 80 + s_idx]);
        state = state * __expf(dt_v * A_s) + dt_v * u_v * B_v;
        float yp = state * C_v;
        yp += __shfl_xor(yp, 1);
        yp += __shfl_xor(yp, 2);
        yp += __shfl_xor(yp, 4);
        yp += __shfl_xor(yp, 8);
        if (s_idx == 0){
            float z  = b2f(xz[(size_t)row*(2*DI_) + DI_ + d]);
            float sz = z / (1.f + __expf(-z));
            xz[(size_t)row*(2*DI_) + d] = f2b((yp + u_v * Dv) * sz);
        }
    }
}

// ---------------- mem-token positions (stable order): one block per batch
__global__ void pos_kernel(const int* __restrict__ ids, int* __restrict__ pos)
{
    int b = blockIdx.x;
    __shared__ int cnt[256];
    int t = threadIdx.x;
    int local = 0;
    #pragma unroll
    for (int i=0;i<4;i++)
        if (ids[b*L_ + t*4 + i] == MEMID) local++;
    cnt[t] = local;
    __syncthreads();
    if (t == 0){
        int run = 0;
        for (int i=0;i<256;i++){ int tmp = cnt[i]; cnt[i] = run; run += tmp; }
    }
    __syncthreads();
    int rank = cnt[t];
    #pragma unroll
    for (int i=0;i<4;i++){
        int l = t*4 + i;
        if (ids[b*L_ + l] == MEMID){
            if (rank < KTOK) pos[b*KTOK + rank] = l;
            rank++;
        }
    }
}

// ---------------- gather + final rmsnorm for the 64 selected rows
__global__ void featnorm_kernel(const float* __restrict__ h,
                                const float* __restrict__ w,
                                const int* __restrict__ pos,
                                bf16* __restrict__ feats)
{
    int bk = blockIdx.x;                        // b*16+k
    int row = (bk >> 4) * L_ + pos[bk];
    const float* x = h + (size_t)row * H_;
    float v[4]; float ss = 0.f;
    #pragma unroll
    for (int i = 0; i < 4; i++){ v[i] = x[threadIdx.x + 256*i]; ss += v[i]*v[i]; }
    #pragma unroll
    for (int off = 32; off; off >>= 1) ss += __shfl_down(ss, off, 64);
    __shared__ float red[4];
    __shared__ float scale_s;
    int lane = threadIdx.x & 63, wv = threadIdx.x >> 6;
    if (lane == 0) red[wv] = ss;
    __syncthreads();
    if (threadIdx.x == 0){
        float t = red[0]+red[1]+red[2]+red[3];
        scale_s = rsqrtf(t * (1.f/H_) + 1e-5f);
    }
    __syncthreads();
    float sc = scale_s;
    #pragma unroll
    for (int i = 0; i < 4; i++){
        int c = threadIdx.x + 256*i;
        feats[(size_t)bk*H_ + c] = f2b(v[i] * sc * w[c]);
    }
}

extern "C" void kernel_launch(void* const* d_in, const int* in_sizes, int n_in,
                              void* d_out, int out_size, void* d_ws, size_t ws_size,
                              hipStream_t stream)
{
    const int*   ids    = (const int*)  d_in[0];
    const float* emb    = (const float*)d_in[1];
    const float* norm_w = (const float*)d_in[2];
    const float* in_w   = (const float*)d_in[3];
    const float* cw     = (const float*)d_in[4];
    const float* cb     = (const float*)d_in[5];
    const float* xw     = (const float*)d_in[6];
    const float* dtw    = (const float*)d_in[7];
    const float* dtb    = (const float*)d_in[8];
    const float* A_log  = (const float*)d_in[9];
    const float* Dp     = (const float*)d_in[10];
    const float* ow     = (const float*)d_in[11];
    const float* fnw    = (const float*)d_in[12];
    const float* projw  = (const float*)d_in[13];
    const float* projb  = (const float*)d_in[14];
    float* out          = (float*)d_out;

    // workspace layout (bytes); total ~106.5 MB
    char* ws = (char*)d_ws;
    float* h    = (float*)(ws + 0);                      // 4096x1024 f32  = 16.78 MB
    bf16*  xn   = (bf16*) (ws + 16777216);               // 4096x1024 bf16 =  8.39 MB
    bf16*  xz   = (bf16*) (ws + 25165824);               // 4096x4096 bf16 = 33.55 MB (x-half reused as gated y)
    bf16*  u    = (bf16*) (ws + 58720256);               // 4096x2048 bf16 = 16.78 MB
    bf16*  ssm  = (bf16*) (ws + 75497472);               // 4096x96 bf16   =  0.79 MB
    bf16*  dt   = (bf16*) (ws + 76283904);               // 4096x2048 bf16 = 16.78 MB
    bf16*  fe   = (bf16*) (ws + 93061120);               // 64x1024 bf16   =  0.13 MB
    int*   pos  = (int*)  (ws + 93192192);               // 64 ints
    // per-layer bf16 weight scratch (reused each layer; projw reuses wb_in at end)
    bf16*  wb_in  = (bf16*)(ws + 93192448);              // 2*DI*H   = 4.19M el = 8.39 MB
    bf16*  wb_ow  = (bf16*)(ws + 101581056);             // H*DI     = 2.10M el = 4.19 MB
    bf16*  wb_xw  = (bf16*)(ws + 105775360);             // 96*DI    = 196K el  = 0.39 MB
    bf16*  wb_dtw = (bf16*)(ws + 106168576);             // DI*DTR   = 131K el  = 0.26 MB
                                                         // end @ 106430720

    embed_kernel<<<MROWS, 256, 0, stream>>>(ids, emb, h);

    const int n_in_w  = 2*DI_*H_;     // 4,194,304
    const int n_ow_w  = H_*DI_;       // 2,097,152
    const int n_xw_w  = 96*DI_;       // 196,608
    const int n_dtw_w = DI_*DTR_;     // 131,072

    for (int l = 0; l < NL_; l++){
        const float* nw_l  = norm_w + l*H_;
        const float* cw_l  = cw     + l*DI_*4;
        const float* cb_l  = cb     + l*DI_;
        const float* dtb_l = dtb    + l*DI_;
        const float* al_l  = A_log  + l*DI_*DS_;
        const float* Dp_l  = Dp     + l*DI_;

        // convert this layer's big weights to bf16
        cvt_kernel<<<(n_in_w+255)/256, 256, 0, stream>>>(in_w + (size_t)l*n_in_w, wb_in, n_in_w);
        cvt_kernel<<<(n_ow_w+255)/256, 256, 0, stream>>>(ow   + (size_t)l*n_ow_w, wb_ow, n_ow_w);
        cvt_kernel<<<(n_xw_w+255)/256, 256, 0, stream>>>(xw   + (size_t)l*n_xw_w, wb_xw, n_xw_w);
        cvt_kernel<<<(n_dtw_w+255)/256, 256, 0, stream>>>(dtw + (size_t)l*n_dtw_w, wb_dtw, n_dtw_w);

        rmsnorm_kernel<<<MROWS, 256, 0, stream>>>(h, nw_l, xn);
        // xz = xn @ in_w^T   (M=4096,N=4096,K=1024) -> bf16
        gemm_bt<<<dim3(32,32), 256, 0, stream>>>(xn, H_, wb_in, H_,
                                                 MROWS, 2*DI_, H_,
                                                 nullptr, xz, 2*DI_, nullptr, 3);
        conv_silu_kernel<<<(MROWS*DI_)/256, 256, 0, stream>>>(xz, cw_l, cb_l, u);
        // ssm = u @ xw^T   (N=96,K=2048) -> bf16
        gemm_bt<<<dim3(1,32), 256, 0, stream>>>(u, DI_, wb_xw, DI_,
                                                MROWS, DTR_+2*DS_, DI_,
                                                nullptr, ssm, 96, nullptr, 3);
        // dt = softplus(ssm[:, :64] @ dtw^T + dtb)  (N=2048,K=64) -> bf16
        gemm_bt<<<dim3(16,32), 256, 0, stream>>>(ssm, 96, wb_dtw, DTR_,
                                                 MROWS, DI_, DTR_,
                                                 nullptr, dt, DI_, dtb_l, 1);
        // scan + gate; gated y written into xz[:, :DI] in-place
        scan_gate_kernel<<<512, 256, 0, stream>>>(dt, u, ssm, al_l, Dp_l, xz);
        // h += y @ ow^T   (N=1024,K=2048) residual in-place f32; A = xz x-half, lda=4096
        gemm_bt<<<dim3(8,32), 256, 0, stream>>>(xz, 2*DI_, wb_ow, DI_,
                                                MROWS, H_, DI_,
                                                h, nullptr, H_, nullptr, 2);
    }

    pos_kernel<<<B_, 256, 0, stream>>>(ids, pos);
    featnorm_kernel<<<B_*KTOK, 256, 0, stream>>>(h, fnw, pos, fe);
    // head weights -> bf16 (reuse wb_in scratch), then out = fe @ proj_w^T + proj_b (f32)
    cvt_kernel<<<(LLM_*H_+255)/256, 256, 0, stream>>>(projw, wb_in, LLM_*H_);
    gemm_bt<<<dim3(32,1), 256, 0, stream>>>(fe, H_, wb_in, H_,
                                            B_*KTOK, LLM_, H_,
                                            out, nullptr, LLM_, projb, 0);
}

// Round 4
// 2309.434 us; speedup vs baseline: 2.1443x; 2.1443x over previous
//
#include <hip/hip_runtime.h>
#include <hip/hip_bf16.h>
#include <cstdint>
#include <cstddef>

// Problem constants
#define H_    1024
#define DI_   2048
#define DS_   16
#define DTR_  64
#define NL_   4
#define LLM_  4096
#define B_    4
#define L_    1024
#define MEMID 50279
#define KTOK  16
#define MROWS (B_*L_)   // 4096

using bf16 = __hip_bfloat16;
typedef __attribute__((ext_vector_type(8))) short short8;
typedef __attribute__((ext_vector_type(4))) short short4v;
typedef __attribute__((ext_vector_type(4))) float floatx4;

__device__ __forceinline__ float b2f(bf16 v){ return __bfloat162float(v); }
__device__ __forceinline__ bf16  f2b(float v){ return __float2bfloat16(v); }
__device__ __forceinline__ float sh2f(short s){
    unsigned u = ((unsigned)(unsigned short)s) << 16;
    return __builtin_bit_cast(float, u);
}
__device__ __forceinline__ short f2sh(float v){
    bf16 b = f2b(v);
    return __builtin_bit_cast(short, b);
}

// ---------------- f32 -> bf16 convert (weights)
__global__ void cvt_kernel(const float* __restrict__ src, bf16* __restrict__ dst, int n)
{
    int i = blockIdx.x*256 + threadIdx.x;
    if (i < n) dst[i] = f2b(src[i]);
}

// ---------------- embed gather
__global__ void embed_kernel(const int* __restrict__ ids,
                             const float* __restrict__ emb,
                             float* __restrict__ h)
{
    int row = blockIdx.x;
    int id  = ids[row];
    const float* src = emb + (size_t)id * H_;
    float* dst = h + (size_t)row * H_;
    for (int i = threadIdx.x; i < H_; i += 256) dst[i] = src[i];
}

// ---------------- rmsnorm over H=1024, one block per row, output bf16
__global__ void rmsnorm_kernel(const float* __restrict__ h,
                               const float* __restrict__ w,
                               bf16* __restrict__ out)
{
    int row = blockIdx.x;
    const float* x = h + (size_t)row * H_;
    float v[4]; float ss = 0.f;
    #pragma unroll
    for (int i = 0; i < 4; i++){ v[i] = x[threadIdx.x + 256*i]; ss += v[i]*v[i]; }
    #pragma unroll
    for (int off = 32; off; off >>= 1) ss += __shfl_down(ss, off, 64);
    __shared__ float red[4];
    __shared__ float scale_s;
    int lane = threadIdx.x & 63, wv = threadIdx.x >> 6;
    if (lane == 0) red[wv] = ss;
    __syncthreads();
    if (threadIdx.x == 0){
        float t = red[0]+red[1]+red[2]+red[3];
        scale_s = rsqrtf(t * (1.f/H_) + 1e-5f);
    }
    __syncthreads();
    float sc = scale_s;
    #pragma unroll
    for (int i = 0; i < 4; i++){
        int c = threadIdx.x + 256*i;
        out[(size_t)row*H_ + c] = f2b(v[i] * sc * w[c]);
    }
}

// ---------------- generic MFMA GEMM: C[m,n] = sum_k A[m,k]*B[n,k]
// mode 0: Cf[m*ldc+n] = acc + bias?[n]           (f32, head)
// mode 1: Cb[n*ldc+m] = bf16(softplus(acc+bias[n]))   TRANSPOSED (dt_t)
// mode 2: Cf[m*ldc+n] += acc                     (f32 residual)
// mode 3: Cb[m*ldc+n] = bf16(acc)                (row-major)
// mode 4: ssm split: n<64 -> Cb[m*64+n] (dtA row-major);
//         64<=n<80 -> pBt[(n-64)*MROWS+m]; 80<=n<96 -> pCt[(n-80)*MROWS+m]
__launch_bounds__(256)
__global__ void gemm_bt(const bf16* __restrict__ A, int lda,
                        const bf16* __restrict__ Bm, int ldb,
                        int M, int N, int K,
                        float* __restrict__ Cf, bf16* __restrict__ Cb, int ldc,
                        const float* __restrict__ bias, int mode,
                        bf16* __restrict__ pBt, bf16* __restrict__ pCt)
{
    int lane = threadIdx.x & 63;
    int wv   = threadIdx.x >> 6;          // 4 waves, 2x2 of 64x64
    int quad = lane >> 4, r16 = lane & 15;
    int m_base = blockIdx.y*128 + (wv>>1)*64;
    int n_base = blockIdx.x*128 + (wv&1)*64;

    floatx4 acc[4][4];
    #pragma unroll
    for (int i=0;i<4;i++)
        #pragma unroll
        for (int j=0;j<4;j++) acc[i][j] = (floatx4){0.f,0.f,0.f,0.f};
    short8 zero8 = (short8){0,0,0,0,0,0,0,0};

    for (int k0 = 0; k0 < K; k0 += 32){
        int kf = k0 + quad*8;
        short8 a[4], b[4];
        #pragma unroll
        for (int i=0;i<4;i++){
            int row = m_base + i*16 + r16;
            a[i] = (row < M) ? *(const short8*)(A + (size_t)row*lda + kf) : zero8;
            int col = n_base + i*16 + r16;
            b[i] = (col < N) ? *(const short8*)(Bm + (size_t)col*ldb + kf) : zero8;
        }
        #pragma unroll
        for (int i=0;i<4;i++)
            #pragma unroll
            for (int j=0;j<4;j++)
                acc[i][j] = __builtin_amdgcn_mfma_f32_16x16x32_bf16(a[i], b[j], acc[i][j], 0, 0, 0);
    }

    #pragma unroll
    for (int i=0;i<4;i++)
        #pragma unroll
        for (int j=0;j<4;j++){
            int mq = m_base + i*16 + quad*4;          // 4 consecutive m
            int n  = n_base + j*16 + r16;
            if (mode == 1){
                if (n < N){
                    short4v pk;
                    #pragma unroll
                    for (int rr=0;rr<4;rr++){
                        float xx = acc[i][j][rr] + bias[n];
                        float sp = (xx > 20.f) ? xx : log1pf(__expf(xx));
                        pk[rr] = f2sh(sp);
                    }
                    *(short4v*)(Cb + (size_t)n*ldc + mq) = pk;
                }
            } else if (mode == 4){
                if (n < 64){
                    #pragma unroll
                    for (int rr=0;rr<4;rr++)
                        Cb[(size_t)(mq+rr)*64 + n] = f2b(acc[i][j][rr]);
                } else if (n < 80){
                    short4v pk;
                    #pragma unroll
                    for (int rr=0;rr<4;rr++) pk[rr] = f2sh(acc[i][j][rr]);
                    *(short4v*)(pBt + (size_t)(n-64)*MROWS + mq) = pk;
                } else if (n < 96){
                    short4v pk;
                    #pragma unroll
                    for (int rr=0;rr<4;rr++) pk[rr] = f2sh(acc[i][j][rr]);
                    *(short4v*)(pCt + (size_t)(n-80)*MROWS + mq) = pk;
                }
            } else {
                #pragma unroll
                for (int rr=0;rr<4;rr++){
                    int m = mq + rr;
                    if (m < M && n < N){
                        float v = acc[i][j][rr];
                        if (mode == 0)      Cf[(size_t)m*ldc + n] = v + (bias ? bias[n] : 0.f);
                        else if (mode == 2) Cf[(size_t)m*ldc + n] += v;
                        else                Cb[(size_t)m*ldc + n] = f2b(v);
                    }
                }
            }
        }
}

// ---------------- causal depthwise conv (k=4) + silu; writes u (row-major) and u_t ([d][bt])
// tile: 64 bt x 64 d per block, LDS transpose for u_t
__global__ void conv_silu_kernel(const bf16* __restrict__ xz,
                                 const float* __restrict__ cw,
                                 const float* __restrict__ cb,
                                 bf16* __restrict__ u,
                                 bf16* __restrict__ u_t)
{
    __shared__ float tile[64][65];
    int bt0 = blockIdx.x * 64;
    int d0  = blockIdx.y * 64;
    int tid = threadIdx.x;
    #pragma unroll
    for (int it = 0; it < 16; it++){
        int idx = it*256 + tid;
        int dd  = idx & 63;          // fast: coalesced over d
        int tr  = idx >> 6;
        int row = bt0 + tr;
        int t   = row & (L_-1);
        int d   = d0 + dd;
        float acc = cb[d];
        #pragma unroll
        for (int k=0;k<4;k++){
            int tt = t - 3 + k;
            if (tt >= 0)
                acc += b2f(xz[(size_t)(row-3+k)*(2*DI_) + d]) * cw[d*4+k];
        }
        float s = acc / (1.f + __expf(-acc));
        u[(size_t)row*DI_ + d] = f2b(s);
        tile[dd][tr] = s;
    }
    __syncthreads();
    #pragma unroll
    for (int it = 0; it < 16; it++){
        int idx = it*256 + tid;
        int tc  = idx & 63;          // fast: coalesced over bt
        int dr  = idx >> 6;
        u_t[(size_t)(d0+dr)*MROWS + bt0 + tc] = f2b(tile[dr][tc]);
    }
}

// ---------------- selective scan, time-vectorized by 8.
// lane = (ch(4) x state(16)) per wave; inputs/outputs all time-major.
__global__ void scan_kernel(const bf16* __restrict__ dt_t,
                            const bf16* __restrict__ u_t,
                            const bf16* __restrict__ sB_t,
                            const bf16* __restrict__ sC_t,
                            const float* __restrict__ A_log,
                            const float* __restrict__ Dp,
                            bf16* __restrict__ y_t)
{
    int lane  = threadIdx.x & 63;
    int wv    = threadIdx.x >> 6;
    int s_idx = lane & 15;
    int ch    = lane >> 4;
    int c = blockIdx.x*16 + wv*4 + ch;      // 0..8191 channel (b,d)
    int d = c & (DI_-1);
    int b = c >> 11;
    float A_s = -__expf(A_log[d*DS_ + s_idx]);
    float Dv  = Dp[d];
    const bf16* dtp = dt_t + (size_t)d*MROWS + b*L_;
    const bf16* utp = u_t  + (size_t)d*MROWS + b*L_;
    const bf16* Bp  = sB_t + (size_t)s_idx*MROWS + b*L_;
    const bf16* Cp  = sC_t + (size_t)s_idx*MROWS + b*L_;
    bf16* yp_ = y_t + (size_t)d*MROWS + b*L_;

    float state = 0.f;
    for (int t0 = 0; t0 < L_; t0 += 8){
        short8 dt8 = *(const short8*)(dtp + t0);
        short8 u8  = *(const short8*)(utp + t0);
        short8 B8  = *(const short8*)(Bp  + t0);
        short8 C8  = *(const short8*)(Cp  + t0);
        short8 yo;
        #pragma unroll
        for (int j = 0; j < 8; j++){
            float dtv = sh2f(dt8[j]);
            float uv  = sh2f(u8[j]);
            float Bv  = sh2f(B8[j]);
            float Cv  = sh2f(C8[j]);
            state = state * __expf(dtv * A_s) + dtv * uv * Bv;
            float yp = state * Cv;
            yp += __shfl_xor(yp, 1);
            yp += __shfl_xor(yp, 2);
            yp += __shfl_xor(yp, 4);
            yp += __shfl_xor(yp, 8);
            yo[j] = f2sh(yp + uv * Dv);
        }
        if (s_idx == 0) *(short8*)(yp_ + t0) = yo;
    }
}

// ---------------- gate + transpose: xz[:, :DI] = y * silu(z)   (y from y_t [d][bt])
__global__ void gate_kernel(const bf16* __restrict__ y_t,
                            bf16* __restrict__ xz)
{
    __shared__ float tile[64][65];
    int bt0 = blockIdx.x * 64;
    int d0  = blockIdx.y * 64;
    int tid = threadIdx.x;
    #pragma unroll
    for (int it = 0; it < 16; it++){
        int idx = it*256 + tid;
        int tc  = idx & 63;
        int dr  = idx >> 6;
        tile[dr][tc] = b2f(y_t[(size_t)(d0+dr)*MROWS + bt0 + tc]);
    }
    __syncthreads();
    #pragma unroll
    for (int it = 0; it < 16; it++){
        int idx = it*256 + tid;
        int dd  = idx & 63;
        int tr  = idx >> 6;
        int row = bt0 + tr;
        float z  = b2f(xz[(size_t)row*(2*DI_) + DI_ + d0 + dd]);
        float sz = z / (1.f + __expf(-z));
        xz[(size_t)row*(2*DI_) + d0 + dd] = f2b(tile[dd][tr] * sz);
    }
}

// ---------------- mem-token positions
__global__ void pos_kernel(const int* __restrict__ ids, int* __restrict__ pos)
{
    int b = blockIdx.x;
    __shared__ int cnt[256];
    int t = threadIdx.x;
    int local = 0;
    #pragma unroll
    for (int i=0;i<4;i++)
        if (ids[b*L_ + t*4 + i] == MEMID) local++;
    cnt[t] = local;
    __syncthreads();
    if (t == 0){
        int run = 0;
        for (int i=0;i<256;i++){ int tmp = cnt[i]; cnt[i] = run; run += tmp; }
    }
    __syncthreads();
    int rank = cnt[t];
    #pragma unroll
    for (int i=0;i<4;i++){
        int l = t*4 + i;
        if (ids[b*L_ + l] == MEMID){
            if (rank < KTOK) pos[b*KTOK + rank] = l;
            rank++;
        }
    }
}

// ---------------- gather + final rmsnorm for the 64 selected rows
__global__ void featnorm_kernel(const float* __restrict__ h,
                                const float* __restrict__ w,
                                const int* __restrict__ pos,
                                bf16* __restrict__ feats)
{
    int bk = blockIdx.x;
    int row = (bk >> 4) * L_ + pos[bk];
    const float* x = h + (size_t)row * H_;
    float v[4]; float ss = 0.f;
    #pragma unroll
    for (int i = 0; i < 4; i++){ v[i] = x[threadIdx.x + 256*i]; ss += v[i]*v[i]; }
    #pragma unroll
    for (int off = 32; off; off >>= 1) ss += __shfl_down(ss, off, 64);
    __shared__ float red[4];
    __shared__ float scale_s;
    int lane = threadIdx.x & 63, wv = threadIdx.x >> 6;
    if (lane == 0) red[wv] = ss;
    __syncthreads();
    if (threadIdx.x == 0){
        float t = red[0]+red[1]+red[2]+red[3];
        scale_s = rsqrtf(t * (1.f/H_) + 1e-5f);
    }
    __syncthreads();
    float sc = scale_s;
    #pragma unroll
    for (int i = 0; i < 4; i++){
        int c = threadIdx.x + 256*i;
        feats[(size_t)bk*H_ + c] = f2b(v[i] * sc * w[c]);
    }
}

extern "C" void kernel_launch(void* const* d_in, const int* in_sizes, int n_in,
                              void* d_out, int out_size, void* d_ws, size_t ws_size,
                              hipStream_t stream)
{
    const int*   ids    = (const int*)  d_in[0];
    const float* emb    = (const float*)d_in[1];
    const float* norm_w = (const float*)d_in[2];
    const float* in_w   = (const float*)d_in[3];
    const float* cw     = (const float*)d_in[4];
    const float* cb     = (const float*)d_in[5];
    const float* xw     = (const float*)d_in[6];
    const float* dtw    = (const float*)d_in[7];
    const float* dtb    = (const float*)d_in[8];
    const float* A_log  = (const float*)d_in[9];
    const float* Dp     = (const float*)d_in[10];
    const float* ow     = (const float*)d_in[11];
    const float* fnw    = (const float*)d_in[12];
    const float* projw  = (const float*)d_in[13];
    const float* projb  = (const float*)d_in[14];
    float* out          = (float*)d_out;

    // workspace layout (bytes); total = 106,430,720 (same as known-good round 3)
    // OVERLAYS: u (row-major) and dt_t both live in [OFF_XN, OFF_XN+16.78MB)
    //   = xn(8.39) + wb_in(8.39); both dead when u/dt_t are live.
    char* ws = (char*)d_ws;
    float* h     = (float*)(ws + 0);             // 16.78 MB
    bf16*  xn    = (bf16*) (ws + 16777216);      //  8.39 MB
    bf16*  wb_in = (bf16*) (ws + 25165824);      //  8.39 MB (also: head proj bf16)
    bf16*  u     = (bf16*) (ws + 16777216);      // 16.78 MB overlay (xn+wb_in)
    bf16*  dt_t  = (bf16*) (ws + 16777216);      // 16.78 MB overlay (same)
    bf16*  xz    = (bf16*) (ws + 33554432);      // 33.55 MB
    bf16*  u_t   = (bf16*) (ws + 67108864);      // 16.78 MB
    bf16*  y_t   = (bf16*) (ws + 83886080);      // 16.78 MB
    bf16*  dtA   = (bf16*) (ws + 100663296);     //  0.52 MB (4096x64)
    bf16*  sB_t  = (bf16*) (ws + 101187584);     //  0.13 MB (16x4096)
    bf16*  sC_t  = (bf16*) (ws + 101318656);     //  0.13 MB
    bf16*  fe    = (bf16*) (ws + 101449728);     //  0.13 MB
    int*   pos   = (int*)  (ws + 101580800);     //  256 B
    bf16*  wb_ow = (bf16*) (ws + 101581056);     //  4.19 MB
    bf16*  wb_xw = (bf16*) (ws + 105775360);     //  0.39 MB
    bf16*  wb_dtw= (bf16*) (ws + 106168576);     //  0.26 MB -> end 106430720

    embed_kernel<<<MROWS, 256, 0, stream>>>(ids, emb, h);

    const int n_in_w  = 2*DI_*H_;
    const int n_ow_w  = H_*DI_;
    const int n_xw_w  = 96*DI_;
    const int n_dtw_w = DI_*DTR_;

    for (int l = 0; l < NL_; l++){
        const float* nw_l  = norm_w + l*H_;
        const float* cw_l  = cw     + l*DI_*4;
        const float* cb_l  = cb     + l*DI_;
        const float* dtb_l = dtb    + l*DI_;
        const float* al_l  = A_log  + l*DI_*DS_;
        const float* Dp_l  = Dp     + l*DI_;

        cvt_kernel<<<(n_in_w+255)/256, 256, 0, stream>>>(in_w + (size_t)l*n_in_w, wb_in, n_in_w);
        cvt_kernel<<<(n_ow_w+255)/256, 256, 0, stream>>>(ow   + (size_t)l*n_ow_w, wb_ow, n_ow_w);
        cvt_kernel<<<(n_xw_w+255)/256, 256, 0, stream>>>(xw   + (size_t)l*n_xw_w, wb_xw, n_xw_w);
        cvt_kernel<<<(n_dtw_w+255)/256, 256, 0, stream>>>(dtw + (size_t)l*n_dtw_w, wb_dtw, n_dtw_w);

        rmsnorm_kernel<<<MROWS, 256, 0, stream>>>(h, nw_l, xn);
        // xz = xn @ in_w^T   (4096x4096x1024) -> bf16 row-major
        gemm_bt<<<dim3(32,32), 256, 0, stream>>>(xn, H_, wb_in, H_,
                                                 MROWS, 2*DI_, H_,
                                                 nullptr, xz, 2*DI_, nullptr, 3, nullptr, nullptr);
        // conv+silu: u row-major (overwrites xn/wb_in region) + u_t time-major
        conv_silu_kernel<<<dim3(MROWS/64, DI_/64), 256, 0, stream>>>(xz, cw_l, cb_l, u, u_t);
        // ssm = u @ xw^T (N=96): dtA row-major, B/C transposed
        gemm_bt<<<dim3(1,32), 256, 0, stream>>>(u, DI_, wb_xw, DI_,
                                                MROWS, DTR_+2*DS_, DI_,
                                                nullptr, dtA, 64, nullptr, 4, sB_t, sC_t);
        // dt_t = softplus(dtA @ dtw^T + dtb), stored TRANSPOSED [d][bt] (overwrites u region)
        gemm_bt<<<dim3(16,32), 256, 0, stream>>>(dtA, DTR_, wb_dtw, DTR_,
                                                 MROWS, DI_, DTR_,
                                                 nullptr, dt_t, MROWS, dtb_l, 1, nullptr, nullptr);
        // scan (time-vectorized x8) -> y_t [d][bt] (D-term folded)
        scan_kernel<<<512, 256, 0, stream>>>(dt_t, u_t, sB_t, sC_t, al_l, Dp_l, y_t);
        // gate+transpose: xz[:, :DI] = y * silu(z)
        gate_kernel<<<dim3(MROWS/64, DI_/64), 256, 0, stream>>>(y_t, xz);
        // h += y_gated @ ow^T  (A = xz x-half, lda=4096)
        gemm_bt<<<dim3(8,32), 256, 0, stream>>>(xz, 2*DI_, wb_ow, DI_,
                                                MROWS, H_, DI_,
                                                h, nullptr, H_, nullptr, 2, nullptr, nullptr);
    }

    pos_kernel<<<B_, 256, 0, stream>>>(ids, pos);
    featnorm_kernel<<<B_*KTOK, 256, 0, stream>>>(h, fnw, pos, fe);
    cvt_kernel<<<(LLM_*H_+255)/256, 256, 0, stream>>>(projw, wb_in, LLM_*H_);
    gemm_bt<<<dim3(32,1), 256, 0, stream>>>(fe, H_, wb_in, H_,
                                            B_*KTOK, LLM_, H_,
                                            out, nullptr, LLM_, projb, 0, nullptr, nullptr);
}

// Round 5
// 1985.846 us; speedup vs baseline: 2.4937x; 1.1629x over previous
//
#include <hip/hip_runtime.h>
#include <hip/hip_bf16.h>
#include <cstdint>
#include <cstddef>

// Problem constants
#define H_    1024
#define DI_   2048
#define DS_   16
#define DTR_  64
#define NL_   4
#define LLM_  4096
#define B_    4
#define L_    1024
#define MEMID 50279
#define KTOK  16
#define MROWS (B_*L_)   // 4096
#define BK    32

using bf16 = __hip_bfloat16;
typedef __attribute__((ext_vector_type(8))) short short8;
typedef __attribute__((ext_vector_type(4))) short short4v;
typedef __attribute__((ext_vector_type(4))) float floatx4;

__device__ __forceinline__ float b2f(bf16 v){ return __bfloat162float(v); }
__device__ __forceinline__ bf16  f2b(float v){ return __float2bfloat16(v); }
__device__ __forceinline__ float sh2f(short s){
    unsigned u = ((unsigned)(unsigned short)s) << 16;
    return __builtin_bit_cast(float, u);
}
__device__ __forceinline__ short f2sh(float v){
    bf16 b = f2b(v);
    return __builtin_bit_cast(short, b);
}

// async global->LDS, 16B per lane; LDS dest = wave-uniform base + lane*16
__device__ __forceinline__ void async16(bf16* l, const bf16* g){
    __builtin_amdgcn_global_load_lds(
        (const __attribute__((address_space(1))) void*)g,
        (__attribute__((address_space(3))) void*)l,
        16, 0, 0);
}

// ---------------- f32 -> bf16 convert (weights)
__global__ void cvt_kernel(const float* __restrict__ src, bf16* __restrict__ dst, int n)
{
    int i = blockIdx.x*256 + threadIdx.x;
    if (i < n) dst[i] = f2b(src[i]);
}

// ---------------- embed gather
__global__ void embed_kernel(const int* __restrict__ ids,
                             const float* __restrict__ emb,
                             float* __restrict__ h)
{
    int row = blockIdx.x;
    int id  = ids[row];
    const float* src = emb + (size_t)id * H_;
    float* dst = h + (size_t)row * H_;
    for (int i = threadIdx.x; i < H_; i += 256) dst[i] = src[i];
}

// ---------------- rmsnorm over H=1024, one block per row, output bf16
__global__ void rmsnorm_kernel(const float* __restrict__ h,
                               const float* __restrict__ w,
                               bf16* __restrict__ out)
{
    int row = blockIdx.x;
    const float* x = h + (size_t)row * H_;
    float v[4]; float ss = 0.f;
    #pragma unroll
    for (int i = 0; i < 4; i++){ v[i] = x[threadIdx.x + 256*i]; ss += v[i]*v[i]; }
    #pragma unroll
    for (int off = 32; off; off >>= 1) ss += __shfl_down(ss, off, 64);
    __shared__ float red[4];
    __shared__ float scale_s;
    int lane = threadIdx.x & 63, wv = threadIdx.x >> 6;
    if (lane == 0) red[wv] = ss;
    __syncthreads();
    if (threadIdx.x == 0){
        float t = red[0]+red[1]+red[2]+red[3];
        scale_s = rsqrtf(t * (1.f/H_) + 1e-5f);
    }
    __syncthreads();
    float sc = scale_s;
    #pragma unroll
    for (int i = 0; i < 4; i++){
        int c = threadIdx.x + 256*i;
        out[(size_t)row*H_ + c] = f2b(v[i] * sc * w[c]);
    }
}

// ---------------- MFMA GEMM, LDS-staged (m97 structure): C[m,n] = sum_k A[m,k]*B[n,k]
// mode 0: Cf[m*ldc+n] = acc + bias?[n]           (f32, head)
// mode 1: Cb[n*ldc+m] = bf16(softplus(acc+bias[n]))   TRANSPOSED (dt_t)
// mode 2: Cf[m*ldc+n] += acc                     (f32 residual)
// mode 3: Cb[m*ldc+n] = bf16(acc)                (row-major)
// mode 4: ssm split: n<64 -> Cb[m*64+n]; 64<=n<80 -> pBt[(n-64)*MROWS+m]; 80<=n<96 -> pCt[(n-80)*MROWS+m]
__launch_bounds__(256)
__global__ void gemm_bt(const bf16* __restrict__ A, int lda,
                        const bf16* __restrict__ Bm, int ldb,
                        int M, int N, int K,
                        float* __restrict__ Cf, bf16* __restrict__ Cb, int ldc,
                        const float* __restrict__ bias, int mode,
                        bf16* __restrict__ pBt, bf16* __restrict__ pCt)
{
    __shared__ __align__(16) bf16 sA[128*BK];
    __shared__ __align__(16) bf16 sB[128*BK];

    int tid  = threadIdx.x;
    int lane = tid & 63;
    int wv   = tid >> 6;          // 4 waves, 2x2 of 64x64
    int quad = lane >> 4, r16 = lane & 15;
    int m0 = blockIdx.y*128, n0 = blockIdx.x*128;
    int wm = (wv>>1)*64, wn = (wv&1)*64;

    // staging: thread t covers rows (t>>2) and (t>>2)+64, k-chunk (t&3)*8 (16B)
    int rr0 = tid >> 2;
    int kc  = (tid & 3) * 8;
    int rA0 = min(m0 + rr0,      M-1);
    int rA1 = min(m0 + rr0 + 64, M-1);
    int rB0 = min(n0 + rr0,      N-1);
    int rB1 = min(n0 + rr0 + 64, N-1);
    const bf16* pA0 = A  + (size_t)rA0*lda + kc;
    const bf16* pA1 = A  + (size_t)rA1*lda + kc;
    const bf16* pB0 = Bm + (size_t)rB0*ldb + kc;
    const bf16* pB1 = Bm + (size_t)rB1*ldb + kc;
    // wave-uniform LDS bases (issue i covers rows i*64..i*64+63 -> bytes i*4096)
    bf16* lA0 = sA + wv*512;
    bf16* lA1 = sA + 2048 + wv*512;
    bf16* lB0 = sB + wv*512;
    bf16* lB1 = sB + 2048 + wv*512;

    floatx4 acc[4][4];
    #pragma unroll
    for (int i=0;i<4;i++)
        #pragma unroll
        for (int j=0;j<4;j++) acc[i][j] = (floatx4){0.f,0.f,0.f,0.f};

    for (int k0 = 0; k0 < K; k0 += BK){
        async16(lA0, pA0);
        async16(lA1, pA1);
        async16(lB0, pB0);
        async16(lB1, pB1);
        pA0 += BK; pA1 += BK; pB0 += BK; pB1 += BK;
        __syncthreads();

        short8 a[4], b[4];
        #pragma unroll
        for (int i=0;i<4;i++)
            a[i] = *(const short8*)(sA + (wm + i*16 + r16)*BK + quad*8);
        #pragma unroll
        for (int j=0;j<4;j++)
            b[j] = *(const short8*)(sB + (wn + j*16 + r16)*BK + quad*8);
        #pragma unroll
        for (int i=0;i<4;i++)
            #pragma unroll
            for (int j=0;j<4;j++)
                acc[i][j] = __builtin_amdgcn_mfma_f32_16x16x32_bf16(a[i], b[j], acc[i][j], 0, 0, 0);
        __syncthreads();
    }

    #pragma unroll
    for (int i=0;i<4;i++)
        #pragma unroll
        for (int j=0;j<4;j++){
            int mq = m0 + wm + i*16 + quad*4;          // 4 consecutive m
            int n  = n0 + wn + j*16 + r16;
            if (mode == 1){
                if (n < N){
                    short4v pk;
                    #pragma unroll
                    for (int rr=0;rr<4;rr++){
                        float xx = acc[i][j][rr] + bias[n];
                        float sp = (xx > 20.f) ? xx : log1pf(__expf(xx));
                        pk[rr] = f2sh(sp);
                    }
                    *(short4v*)(Cb + (size_t)n*ldc + mq) = pk;
                }
            } else if (mode == 4){
                if (n < 64){
                    #pragma unroll
                    for (int rr=0;rr<4;rr++)
                        Cb[(size_t)(mq+rr)*64 + n] = f2b(acc[i][j][rr]);
                } else if (n < 80){
                    short4v pk;
                    #pragma unroll
                    for (int rr=0;rr<4;rr++) pk[rr] = f2sh(acc[i][j][rr]);
                    *(short4v*)(pBt + (size_t)(n-64)*MROWS + mq) = pk;
                } else if (n < 96){
                    short4v pk;
                    #pragma unroll
                    for (int rr=0;rr<4;rr++) pk[rr] = f2sh(acc[i][j][rr]);
                    *(short4v*)(pCt + (size_t)(n-80)*MROWS + mq) = pk;
                }
            } else {
                #pragma unroll
                for (int rr=0;rr<4;rr++){
                    int m = mq + rr;
                    if (m < M && n < N){
                        float v = acc[i][j][rr];
                        if (mode == 0)      Cf[(size_t)m*ldc + n] = v + (bias ? bias[n] : 0.f);
                        else if (mode == 2) Cf[(size_t)m*ldc + n] += v;
                        else                Cb[(size_t)m*ldc + n] = f2b(v);
                    }
                }
            }
        }
}

// ---------------- causal depthwise conv (k=4) + silu; writes u (row-major) and u_t ([d][bt])
__global__ void conv_silu_kernel(const bf16* __restrict__ xz,
                                 const float* __restrict__ cw,
                                 const float* __restrict__ cb,
                                 bf16* __restrict__ u,
                                 bf16* __restrict__ u_t)
{
    __shared__ float tile[64][65];
    int bt0 = blockIdx.x * 64;
    int d0  = blockIdx.y * 64;
    int tid = threadIdx.x;
    #pragma unroll
    for (int it = 0; it < 16; it++){
        int idx = it*256 + tid;
        int dd  = idx & 63;
        int tr  = idx >> 6;
        int row = bt0 + tr;
        int t   = row & (L_-1);
        int d   = d0 + dd;
        float acc = cb[d];
        #pragma unroll
        for (int k=0;k<4;k++){
            int tt = t - 3 + k;
            if (tt >= 0)
                acc += b2f(xz[(size_t)(row-3+k)*(2*DI_) + d]) * cw[d*4+k];
        }
        float s = acc / (1.f + __expf(-acc));
        u[(size_t)row*DI_ + d] = f2b(s);
        tile[dd][tr] = s;
    }
    __syncthreads();
    #pragma unroll
    for (int it = 0; it < 16; it++){
        int idx = it*256 + tid;
        int tc  = idx & 63;
        int dr  = idx >> 6;
        u_t[(size_t)(d0+dr)*MROWS + bt0 + tc] = f2b(tile[dr][tc]);
    }
}

// ---------------- selective scan, time-vectorized by 8
__global__ void scan_kernel(const bf16* __restrict__ dt_t,
                            const bf16* __restrict__ u_t,
                            const bf16* __restrict__ sB_t,
                            const bf16* __restrict__ sC_t,
                            const float* __restrict__ A_log,
                            const float* __restrict__ Dp,
                            bf16* __restrict__ y_t)
{
    int lane  = threadIdx.x & 63;
    int wv    = threadIdx.x >> 6;
    int s_idx = lane & 15;
    int ch    = lane >> 4;
    int c = blockIdx.x*16 + wv*4 + ch;      // 0..8191 channel (b,d)
    int d = c & (DI_-1);
    int b = c >> 11;
    float A_s = -__expf(A_log[d*DS_ + s_idx]);
    float Dv  = Dp[d];
    const bf16* dtp = dt_t + (size_t)d*MROWS + b*L_;
    const bf16* utp = u_t  + (size_t)d*MROWS + b*L_;
    const bf16* Bp  = sB_t + (size_t)s_idx*MROWS + b*L_;
    const bf16* Cp  = sC_t + (size_t)s_idx*MROWS + b*L_;
    bf16* yp_ = y_t + (size_t)d*MROWS + b*L_;

    float state = 0.f;
    for (int t0 = 0; t0 < L_; t0 += 8){
        short8 dt8 = *(const short8*)(dtp + t0);
        short8 u8  = *(const short8*)(utp + t0);
        short8 B8  = *(const short8*)(Bp  + t0);
        short8 C8  = *(const short8*)(Cp  + t0);
        short8 yo;
        #pragma unroll
        for (int j = 0; j < 8; j++){
            float dtv = sh2f(dt8[j]);
            float uv  = sh2f(u8[j]);
            float Bv  = sh2f(B8[j]);
            float Cv  = sh2f(C8[j]);
            state = state * __expf(dtv * A_s) + dtv * uv * Bv;
            float yp = state * Cv;
            yp += __shfl_xor(yp, 1);
            yp += __shfl_xor(yp, 2);
            yp += __shfl_xor(yp, 4);
            yp += __shfl_xor(yp, 8);
            yo[j] = f2sh(yp + uv * Dv);
        }
        if (s_idx == 0) *(short8*)(yp_ + t0) = yo;
    }
}

// ---------------- gate + transpose: xz[:, :DI] = y * silu(z)
__global__ void gate_kernel(const bf16* __restrict__ y_t,
                            bf16* __restrict__ xz)
{
    __shared__ float tile[64][65];
    int bt0 = blockIdx.x * 64;
    int d0  = blockIdx.y * 64;
    int tid = threadIdx.x;
    #pragma unroll
    for (int it = 0; it < 16; it++){
        int idx = it*256 + tid;
        int tc  = idx & 63;
        int dr  = idx >> 6;
        tile[dr][tc] = b2f(y_t[(size_t)(d0+dr)*MROWS + bt0 + tc]);
    }
    __syncthreads();
    #pragma unroll
    for (int it = 0; it < 16; it++){
        int idx = it*256 + tid;
        int dd  = idx & 63;
        int tr  = idx >> 6;
        int row = bt0 + tr;
        float z  = b2f(xz[(size_t)row*(2*DI_) + DI_ + d0 + dd]);
        float sz = z / (1.f + __expf(-z));
        xz[(size_t)row*(2*DI_) + d0 + dd] = f2b(tile[dd][tr] * sz);
    }
}

// ---------------- mem-token positions
__global__ void pos_kernel(const int* __restrict__ ids, int* __restrict__ pos)
{
    int b = blockIdx.x;
    __shared__ int cnt[256];
    int t = threadIdx.x;
    int local = 0;
    #pragma unroll
    for (int i=0;i<4;i++)
        if (ids[b*L_ + t*4 + i] == MEMID) local++;
    cnt[t] = local;
    __syncthreads();
    if (t == 0){
        int run = 0;
        for (int i=0;i<256;i++){ int tmp = cnt[i]; cnt[i] = run; run += tmp; }
    }
    __syncthreads();
    int rank = cnt[t];
    #pragma unroll
    for (int i=0;i<4;i++){
        int l = t*4 + i;
        if (ids[b*L_ + l] == MEMID){
            if (rank < KTOK) pos[b*KTOK + rank] = l;
            rank++;
        }
    }
}

// ---------------- gather + final rmsnorm for the 64 selected rows
__global__ void featnorm_kernel(const float* __restrict__ h,
                                const float* __restrict__ w,
                                const int* __restrict__ pos,
                                bf16* __restrict__ feats)
{
    int bk = blockIdx.x;
    int row = (bk >> 4) * L_ + pos[bk];
    const float* x = h + (size_t)row * H_;
    float v[4]; float ss = 0.f;
    #pragma unroll
    for (int i = 0; i < 4; i++){ v[i] = x[threadIdx.x + 256*i]; ss += v[i]*v[i]; }
    #pragma unroll
    for (int off = 32; off; off >>= 1) ss += __shfl_down(ss, off, 64);
    __shared__ float red[4];
    __shared__ float scale_s;
    int lane = threadIdx.x & 63, wv = threadIdx.x >> 6;
    if (lane == 0) red[wv] = ss;
    __syncthreads();
    if (threadIdx.x == 0){
        float t = red[0]+red[1]+red[2]+red[3];
        scale_s = rsqrtf(t * (1.f/H_) + 1e-5f);
    }
    __syncthreads();
    float sc = scale_s;
    #pragma unroll
    for (int i = 0; i < 4; i++){
        int c = threadIdx.x + 256*i;
        feats[(size_t)bk*H_ + c] = f2b(v[i] * sc * w[c]);
    }
}

extern "C" void kernel_launch(void* const* d_in, const int* in_sizes, int n_in,
                              void* d_out, int out_size, void* d_ws, size_t ws_size,
                              hipStream_t stream)
{
    const int*   ids    = (const int*)  d_in[0];
    const float* emb    = (const float*)d_in[1];
    const float* norm_w = (const float*)d_in[2];
    const float* in_w   = (const float*)d_in[3];
    const float* cw     = (const float*)d_in[4];
    const float* cb     = (const float*)d_in[5];
    const float* xw     = (const float*)d_in[6];
    const float* dtw    = (const float*)d_in[7];
    const float* dtb    = (const float*)d_in[8];
    const float* A_log  = (const float*)d_in[9];
    const float* Dp     = (const float*)d_in[10];
    const float* ow     = (const float*)d_in[11];
    const float* fnw    = (const float*)d_in[12];
    const float* projw  = (const float*)d_in[13];
    const float* projb  = (const float*)d_in[14];
    float* out          = (float*)d_out;

    // workspace layout (bytes); total = 106,430,720 (known-good)
    char* ws = (char*)d_ws;
    float* h     = (float*)(ws + 0);             // 16.78 MB
    bf16*  xn    = (bf16*) (ws + 16777216);      //  8.39 MB
    bf16*  wb_in = (bf16*) (ws + 25165824);      //  8.39 MB (also: head proj bf16)
    bf16*  u     = (bf16*) (ws + 16777216);      // 16.78 MB overlay (xn+wb_in)
    bf16*  dt_t  = (bf16*) (ws + 16777216);      // 16.78 MB overlay (same)
    bf16*  xz    = (bf16*) (ws + 33554432);      // 33.55 MB
    bf16*  u_t   = (bf16*) (ws + 67108864);      // 16.78 MB
    bf16*  y_t   = (bf16*) (ws + 83886080);      // 16.78 MB
    bf16*  dtA   = (bf16*) (ws + 100663296);     //  0.52 MB (4096x64)
    bf16*  sB_t  = (bf16*) (ws + 101187584);     //  0.13 MB (16x4096)
    bf16*  sC_t  = (bf16*) (ws + 101318656);     //  0.13 MB
    bf16*  fe    = (bf16*) (ws + 101449728);     //  0.13 MB
    int*   pos   = (int*)  (ws + 101580800);     //  256 B
    bf16*  wb_ow = (bf16*) (ws + 101581056);     //  4.19 MB
    bf16*  wb_xw = (bf16*) (ws + 105775360);     //  0.39 MB
    bf16*  wb_dtw= (bf16*) (ws + 106168576);     //  0.26 MB -> end 106430720

    embed_kernel<<<MROWS, 256, 0, stream>>>(ids, emb, h);

    const int n_in_w  = 2*DI_*H_;
    const int n_ow_w  = H_*DI_;
    const int n_xw_w  = 96*DI_;
    const int n_dtw_w = DI_*DTR_;

    for (int l = 0; l < NL_; l++){
        const float* nw_l  = norm_w + l*H_;
        const float* cw_l  = cw     + l*DI_*4;
        const float* cb_l  = cb     + l*DI_;
        const float* dtb_l = dtb    + l*DI_;
        const float* al_l  = A_log  + l*DI_*DS_;
        const float* Dp_l  = Dp     + l*DI_;

        cvt_kernel<<<(n_in_w+255)/256, 256, 0, stream>>>(in_w + (size_t)l*n_in_w, wb_in, n_in_w);
        cvt_kernel<<<(n_ow_w+255)/256, 256, 0, stream>>>(ow   + (size_t)l*n_ow_w, wb_ow, n_ow_w);
        cvt_kernel<<<(n_xw_w+255)/256, 256, 0, stream>>>(xw   + (size_t)l*n_xw_w, wb_xw, n_xw_w);
        cvt_kernel<<<(n_dtw_w+255)/256, 256, 0, stream>>>(dtw + (size_t)l*n_dtw_w, wb_dtw, n_dtw_w);

        rmsnorm_kernel<<<MROWS, 256, 0, stream>>>(h, nw_l, xn);
        // xz = xn @ in_w^T   (4096x4096x1024) -> bf16 row-major
        gemm_bt<<<dim3(32,32), 256, 0, stream>>>(xn, H_, wb_in, H_,
                                                 MROWS, 2*DI_, H_,
                                                 nullptr, xz, 2*DI_, nullptr, 3, nullptr, nullptr);
        // conv+silu: u row-major (overwrites xn/wb_in region) + u_t time-major
        conv_silu_kernel<<<dim3(MROWS/64, DI_/64), 256, 0, stream>>>(xz, cw_l, cb_l, u, u_t);
        // ssm = u @ xw^T (N=96): dtA row-major, B/C transposed
        gemm_bt<<<dim3(1,32), 256, 0, stream>>>(u, DI_, wb_xw, DI_,
                                                MROWS, DTR_+2*DS_, DI_,
                                                nullptr, dtA, 64, nullptr, 4, sB_t, sC_t);
        // dt_t = softplus(dtA @ dtw^T + dtb), stored TRANSPOSED [d][bt]
        gemm_bt<<<dim3(16,32), 256, 0, stream>>>(dtA, DTR_, wb_dtw, DTR_,
                                                 MROWS, DI_, DTR_,
                                                 nullptr, dt_t, MROWS, dtb_l, 1, nullptr, nullptr);
        // scan (time-vectorized x8) -> y_t [d][bt]
        scan_kernel<<<512, 256, 0, stream>>>(dt_t, u_t, sB_t, sC_t, al_l, Dp_l, y_t);
        // gate+transpose: xz[:, :DI] = y * silu(z)
        gate_kernel<<<dim3(MROWS/64, DI_/64), 256, 0, stream>>>(y_t, xz);
        // h += y_gated @ ow^T  (A = xz x-half, lda=4096)
        gemm_bt<<<dim3(8,32), 256, 0, stream>>>(xz, 2*DI_, wb_ow, DI_,
                                                MROWS, H_, DI_,
                                                h, nullptr, H_, nullptr, 2, nullptr, nullptr);
    }

    pos_kernel<<<B_, 256, 0, stream>>>(ids, pos);
    featnorm_kernel<<<B_*KTOK, 256, 0, stream>>>(h, fnw, pos, fe);
    cvt_kernel<<<(LLM_*H_+255)/256, 256, 0, stream>>>(projw, wb_in, LLM_*H_);
    gemm_bt<<<dim3(32,1), 256, 0, stream>>>(fe, H_, wb_in, H_,
                                            B_*KTOK, LLM_, H_,
                                            out, nullptr, LLM_, projb, 0, nullptr, nullptr);
}

// Round 6
// 1915.456 us; speedup vs baseline: 2.5854x; 1.0367x over previous
//
#include <hip/hip_runtime.h>
#include <hip/hip_bf16.h>
#include <cstdint>
#include <cstddef>

// Problem constants
#define H_    1024
#define DI_   2048
#define DS_   16
#define DTR_  64
#define NL_   4
#define LLM_  4096
#define B_    4
#define L_    1024
#define MEMID 50279
#define KTOK  16
#define MROWS (B_*L_)   // 4096
#define BK    32

using bf16 = __hip_bfloat16;
typedef __attribute__((ext_vector_type(8))) short short8;
typedef __attribute__((ext_vector_type(4))) short short4v;
typedef __attribute__((ext_vector_type(4))) float floatx4;

__device__ __forceinline__ float b2f(bf16 v){ return __bfloat162float(v); }
__device__ __forceinline__ bf16  f2b(float v){ return __float2bfloat16(v); }
__device__ __forceinline__ float sh2f(short s){
    unsigned u = ((unsigned)(unsigned short)s) << 16;
    return __builtin_bit_cast(float, u);
}
__device__ __forceinline__ short f2sh(float v){
    bf16 b = f2b(v);
    return __builtin_bit_cast(short, b);
}

// sum across a 16-lane DPP row via row_shr; result valid in lane 15 of each row
__device__ __forceinline__ float row_sum16(float v){
    int t;
    t = __builtin_amdgcn_update_dpp(0, __builtin_bit_cast(int, v), 0x111, 0xf, 0xf, true);
    v += __builtin_bit_cast(float, t);
    t = __builtin_amdgcn_update_dpp(0, __builtin_bit_cast(int, v), 0x112, 0xf, 0xf, true);
    v += __builtin_bit_cast(float, t);
    t = __builtin_amdgcn_update_dpp(0, __builtin_bit_cast(int, v), 0x114, 0xf, 0xf, true);
    v += __builtin_bit_cast(float, t);
    t = __builtin_amdgcn_update_dpp(0, __builtin_bit_cast(int, v), 0x118, 0xf, 0xf, true);
    v += __builtin_bit_cast(float, t);
    return v;
}

// async global->LDS, 16B per lane; LDS dest = wave-uniform base + lane*16
__device__ __forceinline__ void async16(bf16* l, const bf16* g){
    __builtin_amdgcn_global_load_lds(
        (const __attribute__((address_space(1))) void*)g,
        (__attribute__((address_space(3))) void*)l,
        16, 0, 0);
}

// ---------------- f32 -> bf16 convert, vectorized x4 (n % 4 == 0)
__global__ void cvt_kernel(const float* __restrict__ src, bf16* __restrict__ dst, int n4)
{
    int i = blockIdx.x*256 + threadIdx.x;
    if (i < n4){
        float4 f = ((const float4*)src)[i];
        short4v o; o[0]=f2sh(f.x); o[1]=f2sh(f.y); o[2]=f2sh(f.z); o[3]=f2sh(f.w);
        ((short4v*)dst)[i] = o;
    }
}

// ---------------- fused 4-segment f32 -> bf16 convert (per-layer weights)
__global__ void cvt4_kernel(const float* __restrict__ s0, bf16* __restrict__ d0, int t0,
                            const float* __restrict__ s1, bf16* __restrict__ d1, int t1,
                            const float* __restrict__ s2, bf16* __restrict__ d2, int t2,
                            const float* __restrict__ s3, bf16* __restrict__ d3, int t3)
{
    int i = blockIdx.x*256 + threadIdx.x;      // float4 index
    const float* s; bf16* d; int local;
    if      (i < t0){ s=s0; d=d0; local=i; }
    else if (i < t1){ s=s1; d=d1; local=i-t0; }
    else if (i < t2){ s=s2; d=d2; local=i-t1; }
    else if (i < t3){ s=s3; d=d3; local=i-t2; }
    else return;
    float4 f = ((const float4*)s)[local];
    short4v o; o[0]=f2sh(f.x); o[1]=f2sh(f.y); o[2]=f2sh(f.z); o[3]=f2sh(f.w);
    ((short4v*)d)[local] = o;
}

// ---------------- embed gather (float4)
__global__ void embed_kernel(const int* __restrict__ ids,
                             const float* __restrict__ emb,
                             float* __restrict__ h)
{
    int row = blockIdx.x;
    int id  = ids[row];
    const float4* src = (const float4*)(emb + (size_t)id * H_);
    float4* dst = (float4*)(h + (size_t)row * H_);
    dst[threadIdx.x] = src[threadIdx.x];
}

// ---------------- rmsnorm over H=1024, one block per row, output bf16
__global__ void rmsnorm_kernel(const float* __restrict__ h,
                               const float* __restrict__ w,
                               bf16* __restrict__ out)
{
    int row = blockIdx.x;
    const float* x = h + (size_t)row * H_;
    float v[4]; float ss = 0.f;
    #pragma unroll
    for (int i = 0; i < 4; i++){ v[i] = x[threadIdx.x + 256*i]; ss += v[i]*v[i]; }
    #pragma unroll
    for (int off = 32; off; off >>= 1) ss += __shfl_down(ss, off, 64);
    __shared__ float red[4];
    __shared__ float scale_s;
    int lane = threadIdx.x & 63, wv = threadIdx.x >> 6;
    if (lane == 0) red[wv] = ss;
    __syncthreads();
    if (threadIdx.x == 0){
        float t = red[0]+red[1]+red[2]+red[3];
        scale_s = rsqrtf(t * (1.f/H_) + 1e-5f);
    }
    __syncthreads();
    float sc = scale_s;
    #pragma unroll
    for (int i = 0; i < 4; i++){
        int c = threadIdx.x + 256*i;
        out[(size_t)row*H_ + c] = f2b(v[i] * sc * w[c]);
    }
}

// ---------------- MFMA GEMM, LDS-staged (m97 structure): C[m,n] = sum_k A[m,k]*B[n,k]
// mode 0: Cf[m*ldc+n] = acc + bias?[n]           (f32, head)
// mode 1: Cb[n*ldc+m] = bf16(softplus(acc+bias[n]))   TRANSPOSED (dt_t)
// mode 2: Cf[m*ldc+n] += acc                     (f32 residual)
// mode 3: Cb[m*ldc+n] = bf16(acc)                (row-major)
// mode 4: ssm split: n<64 -> Cb[m*64+n]; 64<=n<80 -> pBt[(n-64)*MROWS+m]; 80<=n<96 -> pCt[(n-80)*MROWS+m]
__launch_bounds__(256)
__global__ void gemm_bt(const bf16* __restrict__ A, int lda,
                        const bf16* __restrict__ Bm, int ldb,
                        int M, int N, int K,
                        float* __restrict__ Cf, bf16* __restrict__ Cb, int ldc,
                        const float* __restrict__ bias, int mode,
                        bf16* __restrict__ pBt, bf16* __restrict__ pCt)
{
    __shared__ __align__(16) bf16 sA[128*BK];
    __shared__ __align__(16) bf16 sB[128*BK];

    int tid  = threadIdx.x;
    int lane = tid & 63;
    int wv   = tid >> 6;          // 4 waves, 2x2 of 64x64
    int quad = lane >> 4, r16 = lane & 15;
    int m0 = blockIdx.y*128, n0 = blockIdx.x*128;
    int wm = (wv>>1)*64, wn = (wv&1)*64;

    int rr0 = tid >> 2;
    int kc  = (tid & 3) * 8;
    int rA0 = min(m0 + rr0,      M-1);
    int rA1 = min(m0 + rr0 + 64, M-1);
    int rB0 = min(n0 + rr0,      N-1);
    int rB1 = min(n0 + rr0 + 64, N-1);
    const bf16* pA0 = A  + (size_t)rA0*lda + kc;
    const bf16* pA1 = A  + (size_t)rA1*lda + kc;
    const bf16* pB0 = Bm + (size_t)rB0*ldb + kc;
    const bf16* pB1 = Bm + (size_t)rB1*ldb + kc;
    bf16* lA0 = sA + wv*512;
    bf16* lA1 = sA + 2048 + wv*512;
    bf16* lB0 = sB + wv*512;
    bf16* lB1 = sB + 2048 + wv*512;

    floatx4 acc[4][4];
    #pragma unroll
    for (int i=0;i<4;i++)
        #pragma unroll
        for (int j=0;j<4;j++) acc[i][j] = (floatx4){0.f,0.f,0.f,0.f};

    for (int k0 = 0; k0 < K; k0 += BK){
        async16(lA0, pA0);
        async16(lA1, pA1);
        async16(lB0, pB0);
        async16(lB1, pB1);
        pA0 += BK; pA1 += BK; pB0 += BK; pB1 += BK;
        __syncthreads();

        short8 a[4], b[4];
        #pragma unroll
        for (int i=0;i<4;i++)
            a[i] = *(const short8*)(sA + (wm + i*16 + r16)*BK + quad*8);
        #pragma unroll
        for (int j=0;j<4;j++)
            b[j] = *(const short8*)(sB + (wn + j*16 + r16)*BK + quad*8);
        #pragma unroll
        for (int i=0;i<4;i++)
            #pragma unroll
            for (int j=0;j<4;j++)
                acc[i][j] = __builtin_amdgcn_mfma_f32_16x16x32_bf16(a[i], b[j], acc[i][j], 0, 0, 0);
        __syncthreads();
    }

    #pragma unroll
    for (int i=0;i<4;i++)
        #pragma unroll
        for (int j=0;j<4;j++){
            int mq = m0 + wm + i*16 + quad*4;
            int n  = n0 + wn + j*16 + r16;
            if (mode == 1){
                if (n < N){
                    short4v pk;
                    #pragma unroll
                    for (int rr=0;rr<4;rr++){
                        float xx = acc[i][j][rr] + bias[n];
                        float sp = (xx > 20.f) ? xx : log1pf(__expf(xx));
                        pk[rr] = f2sh(sp);
                    }
                    *(short4v*)(Cb + (size_t)n*ldc + mq) = pk;
                }
            } else if (mode == 4){
                if (n < 64){
                    #pragma unroll
                    for (int rr=0;rr<4;rr++)
                        Cb[(size_t)(mq+rr)*64 + n] = f2b(acc[i][j][rr]);
                } else if (n < 80){
                    short4v pk;
                    #pragma unroll
                    for (int rr=0;rr<4;rr++) pk[rr] = f2sh(acc[i][j][rr]);
                    *(short4v*)(pBt + (size_t)(n-64)*MROWS + mq) = pk;
                } else if (n < 96){
                    short4v pk;
                    #pragma unroll
                    for (int rr=0;rr<4;rr++) pk[rr] = f2sh(acc[i][j][rr]);
                    *(short4v*)(pCt + (size_t)(n-80)*MROWS + mq) = pk;
                }
            } else {
                #pragma unroll
                for (int rr=0;rr<4;rr++){
                    int m = mq + rr;
                    if (m < M && n < N){
                        float v = acc[i][j][rr];
                        if (mode == 0)      Cf[(size_t)m*ldc + n] = v + (bias ? bias[n] : 0.f);
                        else if (mode == 2) Cf[(size_t)m*ldc + n] += v;
                        else                Cb[(size_t)m*ldc + n] = f2b(v);
                    }
                }
            }
        }
}

// ---------------- causal depthwise conv (k=4) + silu; writes u (row-major) and u_t ([d][bt])
__global__ void conv_silu_kernel(const bf16* __restrict__ xz,
                                 const float* __restrict__ cw,
                                 const float* __restrict__ cb,
                                 bf16* __restrict__ u,
                                 bf16* __restrict__ u_t)
{
    __shared__ float tile[64][65];
    int bt0 = blockIdx.x * 64;
    int d0  = blockIdx.y * 64;
    int tid = threadIdx.x;
    #pragma unroll
    for (int it = 0; it < 16; it++){
        int idx = it*256 + tid;
        int dd  = idx & 63;
        int tr  = idx >> 6;
        int row = bt0 + tr;
        int t   = row & (L_-1);
        int d   = d0 + dd;
        float acc = cb[d];
        #pragma unroll
        for (int k=0;k<4;k++){
            int tt = t - 3 + k;
            if (tt >= 0)
                acc += b2f(xz[(size_t)(row-3+k)*(2*DI_) + d]) * cw[d*4+k];
        }
        float s = acc / (1.f + __expf(-acc));
        u[(size_t)row*DI_ + d] = f2b(s);
        tile[dd][tr] = s;
    }
    __syncthreads();
    #pragma unroll
    for (int it = 0; it < 16; it++){
        int idx = it*256 + tid;
        int tc  = idx & 63;
        int dr  = idx >> 6;
        u_t[(size_t)(d0+dr)*MROWS + bt0 + tc] = f2b(tile[dr][tc]);
    }
}

// ---------------- selective scan, time-vectorized x8, DPP reduction, prefetched
__global__ void scan_kernel(const bf16* __restrict__ dt_t,
                            const bf16* __restrict__ u_t,
                            const bf16* __restrict__ sB_t,
                            const bf16* __restrict__ sC_t,
                            const float* __restrict__ A_log,
                            const float* __restrict__ Dp,
                            bf16* __restrict__ y_t)
{
    int lane  = threadIdx.x & 63;
    int wv    = threadIdx.x >> 6;
    int s_idx = lane & 15;
    int ch    = lane >> 4;
    int c = blockIdx.x*16 + wv*4 + ch;      // 0..8191 channel (b,d)
    int d = c & (DI_-1);
    int b = c >> 11;
    float A_s = -__expf(A_log[d*DS_ + s_idx]);
    float Dv  = Dp[d];
    const short8* dtp = (const short8*)(dt_t + (size_t)d*MROWS + b*L_);
    const short8* utp = (const short8*)(u_t  + (size_t)d*MROWS + b*L_);
    const short8* Bp  = (const short8*)(sB_t + (size_t)s_idx*MROWS + b*L_);
    const short8* Cp  = (const short8*)(sC_t + (size_t)s_idx*MROWS + b*L_);
    short8* yp_ = (short8*)(y_t + (size_t)d*MROWS + b*L_);

    float state = 0.f;
    short8 dt8 = dtp[0], u8 = utp[0], B8 = Bp[0], C8 = Cp[0];
    for (int g = 0; g < L_/8; g++){
        int gn = (g+1 < L_/8) ? g+1 : g;
        short8 ndt = dtp[gn], nu = utp[gn], nB = Bp[gn], nC = Cp[gn];
        short8 yo;
        #pragma unroll
        for (int j = 0; j < 8; j++){
            float dtv = sh2f(dt8[j]);
            float uv  = sh2f(u8[j]);
            float Bv  = sh2f(B8[j]);
            float Cv  = sh2f(C8[j]);
            state = state * __expf(dtv * A_s) + dtv * uv * Bv;
            float yp = row_sum16(state * Cv);     // valid in lane 15 of each row
            yo[j] = f2sh(yp + uv * Dv);
        }
        if (s_idx == 15) yp_[g] = yo;
        dt8 = ndt; u8 = nu; B8 = nB; C8 = nC;
    }
}

// ---------------- gate + transpose: xz[:, :DI] = y * silu(z)
__global__ void gate_kernel(const bf16* __restrict__ y_t,
                            bf16* __restrict__ xz)
{
    __shared__ float tile[64][65];
    int bt0 = blockIdx.x * 64;
    int d0  = blockIdx.y * 64;
    int tid = threadIdx.x;
    #pragma unroll
    for (int it = 0; it < 16; it++){
        int idx = it*256 + tid;
        int tc  = idx & 63;
        int dr  = idx >> 6;
        tile[dr][tc] = b2f(y_t[(size_t)(d0+dr)*MROWS + bt0 + tc]);
    }
    __syncthreads();
    #pragma unroll
    for (int it = 0; it < 16; it++){
        int idx = it*256 + tid;
        int dd  = idx & 63;
        int tr  = idx >> 6;
        int row = bt0 + tr;
        float z  = b2f(xz[(size_t)row*(2*DI_) + DI_ + d0 + dd]);
        float sz = z / (1.f + __expf(-z));
        xz[(size_t)row*(2*DI_) + d0 + dd] = f2b(tile[dd][tr] * sz);
    }
}

// ---------------- mem-token positions
__global__ void pos_kernel(const int* __restrict__ ids, int* __restrict__ pos)
{
    int b = blockIdx.x;
    __shared__ int cnt[256];
    int t = threadIdx.x;
    int local = 0;
    #pragma unroll
    for (int i=0;i<4;i++)
        if (ids[b*L_ + t*4 + i] == MEMID) local++;
    cnt[t] = local;
    __syncthreads();
    if (t == 0){
        int run = 0;
        for (int i=0;i<256;i++){ int tmp = cnt[i]; cnt[i] = run; run += tmp; }
    }
    __syncthreads();
    int rank = cnt[t];
    #pragma unroll
    for (int i=0;i<4;i++){
        int l = t*4 + i;
        if (ids[b*L_ + l] == MEMID){
            if (rank < KTOK) pos[b*KTOK + rank] = l;
            rank++;
        }
    }
}

// ---------------- gather + final rmsnorm for the 64 selected rows
__global__ void featnorm_kernel(const float* __restrict__ h,
                                const float* __restrict__ w,
                                const int* __restrict__ pos,
                                bf16* __restrict__ feats)
{
    int bk = blockIdx.x;
    int row = (bk >> 4) * L_ + pos[bk];
    const float* x = h + (size_t)row * H_;
    float v[4]; float ss = 0.f;
    #pragma unroll
    for (int i = 0; i < 4; i++){ v[i] = x[threadIdx.x + 256*i]; ss += v[i]*v[i]; }
    #pragma unroll
    for (int off = 32; off; off >>= 1) ss += __shfl_down(ss, off, 64);
    __shared__ float red[4];
    __shared__ float scale_s;
    int lane = threadIdx.x & 63, wv = threadIdx.x >> 6;
    if (lane == 0) red[wv] = ss;
    __syncthreads();
    if (threadIdx.x == 0){
        float t = red[0]+red[1]+red[2]+red[3];
        scale_s = rsqrtf(t * (1.f/H_) + 1e-5f);
    }
    __syncthreads();
    float sc = scale_s;
    #pragma unroll
    for (int i = 0; i < 4; i++){
        int c = threadIdx.x + 256*i;
        feats[(size_t)bk*H_ + c] = f2b(v[i] * sc * w[c]);
    }
}

extern "C" void kernel_launch(void* const* d_in, const int* in_sizes, int n_in,
                              void* d_out, int out_size, void* d_ws, size_t ws_size,
                              hipStream_t stream)
{
    const int*   ids    = (const int*)  d_in[0];
    const float* emb    = (const float*)d_in[1];
    const float* norm_w = (const float*)d_in[2];
    const float* in_w   = (const float*)d_in[3];
    const float* cw     = (const float*)d_in[4];
    const float* cb     = (const float*)d_in[5];
    const float* xw     = (const float*)d_in[6];
    const float* dtw    = (const float*)d_in[7];
    const float* dtb    = (const float*)d_in[8];
    const float* A_log  = (const float*)d_in[9];
    const float* Dp     = (const float*)d_in[10];
    const float* ow     = (const float*)d_in[11];
    const float* fnw    = (const float*)d_in[12];
    const float* projw  = (const float*)d_in[13];
    const float* projb  = (const float*)d_in[14];
    float* out          = (float*)d_out;

    // workspace layout (bytes); total = 106,430,720 (known-good)
    char* ws = (char*)d_ws;
    float* h     = (float*)(ws + 0);             // 16.78 MB
    bf16*  xn    = (bf16*) (ws + 16777216);      //  8.39 MB
    bf16*  wb_in = (bf16*) (ws + 25165824);      //  8.39 MB (also: head proj bf16)
    bf16*  u     = (bf16*) (ws + 16777216);      // 16.78 MB overlay (xn+wb_in)
    bf16*  dt_t  = (bf16*) (ws + 16777216);      // 16.78 MB overlay (same)
    bf16*  xz    = (bf16*) (ws + 33554432);      // 33.55 MB
    bf16*  u_t   = (bf16*) (ws + 67108864);      // 16.78 MB
    bf16*  y_t   = (bf16*) (ws + 83886080);      // 16.78 MB
    bf16*  dtA   = (bf16*) (ws + 100663296);     //  0.52 MB (4096x64)
    bf16*  sB_t  = (bf16*) (ws + 101187584);     //  0.13 MB (16x4096)
    bf16*  sC_t  = (bf16*) (ws + 101318656);     //  0.13 MB
    bf16*  fe    = (bf16*) (ws + 101449728);     //  0.13 MB
    int*   pos   = (int*)  (ws + 101580800);     //  256 B
    bf16*  wb_ow = (bf16*) (ws + 101581056);     //  4.19 MB
    bf16*  wb_xw = (bf16*) (ws + 105775360);     //  0.39 MB
    bf16*  wb_dtw= (bf16*) (ws + 106168576);     //  0.26 MB -> end 106430720

    embed_kernel<<<MROWS, 256, 0, stream>>>(ids, emb, h);

    const int n_in_w  = 2*DI_*H_;     // 4,194,304
    const int n_ow_w  = H_*DI_;       // 2,097,152
    const int n_xw_w  = 96*DI_;       // 196,608
    const int n_dtw_w = DI_*DTR_;     // 131,072
    const int t0c = n_in_w>>2;
    const int t1c = t0c + (n_ow_w>>2);
    const int t2c = t1c + (n_xw_w>>2);
    const int t3c = t2c + (n_dtw_w>>2);   // 1,654,784

    for (int l = 0; l < NL_; l++){
        const float* nw_l  = norm_w + l*H_;
        const float* cw_l  = cw     + l*DI_*4;
        const float* cb_l  = cb     + l*DI_;
        const float* dtb_l = dtb    + l*DI_;
        const float* al_l  = A_log  + l*DI_*DS_;
        const float* Dp_l  = Dp     + l*DI_;

        cvt4_kernel<<<(t3c+255)/256, 256, 0, stream>>>(
            in_w + (size_t)l*n_in_w, wb_in, t0c,
            ow   + (size_t)l*n_ow_w, wb_ow, t1c,
            xw   + (size_t)l*n_xw_w, wb_xw, t2c,
            dtw  + (size_t)l*n_dtw_w, wb_dtw, t3c);

        rmsnorm_kernel<<<MROWS, 256, 0, stream>>>(h, nw_l, xn);
        // xz = xn @ in_w^T   (4096x4096x1024) -> bf16 row-major
        gemm_bt<<<dim3(32,32), 256, 0, stream>>>(xn, H_, wb_in, H_,
                                                 MROWS, 2*DI_, H_,
                                                 nullptr, xz, 2*DI_, nullptr, 3, nullptr, nullptr);
        // conv+silu: u row-major (overwrites xn/wb_in region) + u_t time-major
        conv_silu_kernel<<<dim3(MROWS/64, DI_/64), 256, 0, stream>>>(xz, cw_l, cb_l, u, u_t);
        // ssm = u @ xw^T (N=96): dtA row-major, B/C transposed
        gemm_bt<<<dim3(1,32), 256, 0, stream>>>(u, DI_, wb_xw, DI_,
                                                MROWS, DTR_+2*DS_, DI_,
                                                nullptr, dtA, 64, nullptr, 4, sB_t, sC_t);
        // dt_t = softplus(dtA @ dtw^T + dtb), stored TRANSPOSED [d][bt]
        gemm_bt<<<dim3(16,32), 256, 0, stream>>>(dtA, DTR_, wb_dtw, DTR_,
                                                 MROWS, DI_, DTR_,
                                                 nullptr, dt_t, MROWS, dtb_l, 1, nullptr, nullptr);
        // scan (time-vectorized x8, DPP reduce) -> y_t [d][bt]
        scan_kernel<<<512, 256, 0, stream>>>(dt_t, u_t, sB_t, sC_t, al_l, Dp_l, y_t);
        // gate+transpose: xz[:, :DI] = y * silu(z)
        gate_kernel<<<dim3(MROWS/64, DI_/64), 256, 0, stream>>>(y_t, xz);
        // h += y_gated @ ow^T  (A = xz x-half, lda=4096)
        gemm_bt<<<dim3(8,32), 256, 0, stream>>>(xz, 2*DI_, wb_ow, DI_,
                                                MROWS, H_, DI_,
                                                h, nullptr, H_, nullptr, 2, nullptr, nullptr);
    }

    pos_kernel<<<B_, 256, 0, stream>>>(ids, pos);
    featnorm_kernel<<<B_*KTOK, 256, 0, stream>>>(h, fnw, pos, fe);
    cvt_kernel<<<((LLM_*H_/4)+255)/256, 256, 0, stream>>>(projw, wb_in, LLM_*H_/4);
    gemm_bt<<<dim3(32,1), 256, 0, stream>>>(fe, H_, wb_in, H_,
                                            B_*KTOK, LLM_, H_,
                                            out, nullptr, LLM_, projb, 0, nullptr, nullptr);
}